// Round 25
// baseline (430.087 us; speedup 1.0000x reference)
//
#include <hip/hip_runtime.h>
#include <hip/hip_fp8.h>

// EncoderBlock: B=8, S=2048, D=1024, H=4096, single-head attn (scale AFTER softmax),
// LN -> QKV -> scores -> softmax*(1/32) -> PV -> MLP(Swish) -> +residual.
// Round 25: R24 base (393.8us) + ONE concept: operand-swapped MFMA -> C^T fragments
// -> PACKED epilogue stores. mfma(bv,av) makes each lane hold 4 consecutive C-columns
// of one row (A/B fragment symmetry, relied on + validated since R23), so every
// epilogue shrinks 4x: fp8 -> u32 packed store, f16 -> f16x4 8B store, f32 RESID ->
// float4 LMS. Main loop unchanged. Everything else identical: MX fp8 (16x16x128,
// unit scales), BK=128 dbuf 64KiB, counted-vmcnt 2-deep, 2 blocks/CU, band raster,
// fused QKV. WS = 190,840,832 B; overlay identical to R17/R22/R23.

#define Bb_ 8
#define Ss_ 2048
#define Dd_ 1024
#define Hh_ 4096

typedef __bf16 bf16;
typedef _Float16 f16;
typedef unsigned char u8;
typedef unsigned int u32;
typedef unsigned long long u64;
typedef __attribute__((ext_vector_type(8))) _Float16 f16x8;
typedef __attribute__((ext_vector_type(4))) _Float16 f16x4;
typedef __attribute__((ext_vector_type(4))) float f32x4;
typedef __attribute__((ext_vector_type(4))) int i32x4;
typedef __attribute__((ext_vector_type(8))) int i32x8;

enum { EPI_QKV = 0, EPI_SCORE = 1, EPI_AOS = 2, EPI_SWISH = 3, EPI_RESID = 4 };

__device__ __forceinline__ void gload16(const void* g, void* l) {
  __builtin_amdgcn_global_load_lds(
      (const __attribute__((address_space(1))) void*)g,
      (__attribute__((address_space(3))) void*)l, 16, 0, 0);
}

__device__ __forceinline__ u8 to_fp8(float f) {
  __hip_fp8_e4m3 v(f);  // OCP e4m3fn (gfx950 native)
  return (u8)v.__x;
}

__device__ __forceinline__ u32 pack4fp8(float a, float b, float c, float d) {
  return (u32)to_fp8(a) | ((u32)to_fp8(b) << 8) |
         ((u32)to_fp8(c) << 16) | ((u32)to_fp8(d) << 24);
}

#define SETP(x) __builtin_amdgcn_s_setprio(x)
#define BARRIER()                          \
  do {                                     \
    asm volatile("" ::: "memory");         \
    __builtin_amdgcn_s_barrier();          \
    asm volatile("" ::: "memory");         \
  } while (0)
#define VMC(n) asm volatile("s_waitcnt vmcnt(" #n ")" ::: "memory")

// ---------- transpose-cast: W[K][N] f32 -> WT[N][K] fp8 e4m3 ----------
__global__ __launch_bounds__(256) void tcast8_k(const float* __restrict__ W,
                                                u8* __restrict__ WT, int K, int N) {
  __shared__ float tile[32][33];
  const int tn0 = blockIdx.x * 32;
  const int tk0 = blockIdx.y * 32;
  const int t = threadIdx.x;
  const int c = t & 31;
  const int r4 = t >> 5;
#pragma unroll
  for (int i = 0; i < 4; i++) {
    int r = r4 + i * 8;
    tile[r][c] = W[(long)(tk0 + r) * N + (tn0 + c)];
  }
  __syncthreads();
#pragma unroll
  for (int i = 0; i < 4; i++) {
    int r = r4 + i * 8;
    WT[(long)(tn0 + r) * K + (tk0 + c)] = to_fp8(tile[c][r]);
  }
}

// ---------- v transpose+cast: vrows f16 [z][2048][1024] -> vT8 u8 [z][1024][2048] ----
__global__ __launch_bounds__(256) void tv8_k(const f16* __restrict__ V,
                                             u8* __restrict__ VT) {
  __shared__ f16 tile[64][72];
  const long z = blockIdx.z;
  const int n0 = blockIdx.x * 64;
  const int k0 = blockIdx.y * 64;
  const int t = threadIdx.x;
  const int r = t >> 3;
  const int c = (t & 7) * 8;
  const f16* Vb = V + z * (long)(Ss_ * Dd_);
  u8* VTb = VT + z * (long)(Dd_ * Ss_);
#pragma unroll
  for (int i = 0; i < 2; i++)
    *(f16x8*)&tile[r + i * 32][c] =
        *(const f16x8*)(Vb + (long)(k0 + r + i * 32) * Dd_ + n0 + c);
  __syncthreads();
#pragma unroll
  for (int i = 0; i < 2; i++) {
    const int n = r + i * 32;
    union { u8 b[8]; u64 w; } ov;
#pragma unroll
    for (int j = 0; j < 8; j++) ov.b[j] = to_fp8((float)tile[c + j][n]);
    *(u64*)(VTb + (long)(n0 + n) * Ss_ + k0 + c) = ov.w;
  }
}

// ---------- LayerNorm: x[row][1024] f32 -> xn fp8 ----------
__global__ __launch_bounds__(256) void ln8_k(const float* __restrict__ x,
                                             const float* __restrict__ gamma,
                                             const float* __restrict__ beta,
                                             u8* __restrict__ xn) {
  const long row = blockIdx.x;
  const float* xr = x + row * Dd_;
  const int t = threadIdx.x;
  float4 v = *(const float4*)(xr + t * 4);
  float s = v.x + v.y + v.z + v.w;
  float sq = v.x * v.x + v.y * v.y + v.z * v.z + v.w * v.w;
#pragma unroll
  for (int o = 32; o > 0; o >>= 1) {
    s += __shfl_down(s, o);
    sq += __shfl_down(sq, o);
  }
  __shared__ float ls[4], lq[4];
  const int wid = t >> 6;
  if ((t & 63) == 0) { ls[wid] = s; lq[wid] = sq; }
  __syncthreads();
  if (t == 0) {
    float S = ls[0] + ls[1] + ls[2] + ls[3];
    float Q = lq[0] + lq[1] + lq[2] + lq[3];
    float mu = S * (1.0f / Dd_);
    float var = Q * (1.0f / Dd_) - mu * mu;
    ls[0] = mu;
    lq[0] = rsqrtf(var + 1e-5f);
  }
  __syncthreads();
  const float mu = ls[0], rstd = lq[0];
  float4 g = *(const float4*)(gamma + t * 4);
  float4 be = *(const float4*)(beta + t * 4);
  u32 pk = pack4fp8((v.x - mu) * rstd * g.x + be.x,
                    (v.y - mu) * rstd * g.y + be.y,
                    (v.z - mu) * rstd * g.z + be.z,
                    (v.w - mu) * rstd * g.w + be.w);
  *(u32*)(xn + row * (long)Dd_ + t * 4) = pk;
}

// ---------- softmax: f16 scores (two slabs) -> fp8 probs x256, in place ----------
__global__ __launch_bounds__(256) void softmax8_k(f16* __restrict__ lo,
                                                  f16* __restrict__ hi) {
  const long row = blockIdx.x;
  const long z = row >> 11;
  f16* sr = (z < 4 ? lo + z * 4194304L : hi + (z - 4) * 4194304L) +
            (row & 2047) * (long)Ss_;
  const int t = threadIdx.x;
  f16x8 v = *(const f16x8*)(sr + t * 8);
  float f[8];
#pragma unroll
  for (int j = 0; j < 8; j++) f[j] = (float)v[j];
  float vm = f[0];
#pragma unroll
  for (int j = 1; j < 8; j++) vm = fmaxf(vm, f[j]);
  __shared__ float red[4];
#pragma unroll
  for (int o = 32; o > 0; o >>= 1) vm = fmaxf(vm, __shfl_xor(vm, o));
  const int wid = t >> 6;
  if ((t & 63) == 0) red[wid] = vm;
  __syncthreads();
  vm = fmaxf(fmaxf(red[0], red[1]), fmaxf(red[2], red[3]));
  float e[8], s = 0.f;
#pragma unroll
  for (int j = 0; j < 8; j++) { e[j] = __expf(f[j] - vm); s += e[j]; }
#pragma unroll
  for (int o = 32; o > 0; o >>= 1) s += __shfl_xor(s, o);
  __syncthreads();
  if ((t & 63) == 0) red[wid] = s;
  __syncthreads();
  s = red[0] + red[1] + red[2] + red[3];
  const float rs = 256.0f / s;  // x256: avoids e4m3 subnormals; /8192 in PV epilogue
  union { u32 w[2]; u64 d; } ov;
  ov.w[0] = pack4fp8(e[0] * rs, e[1] * rs, e[2] * rs, e[3] * rs);
  ov.w[1] = pack4fp8(e[4] * rs, e[5] * rs, e[6] * rs, e[7] * rs);
  *(u64*)((u8*)sr + t * 8) = ov.d;
}

// ====== MX fp8 128x128xK GEMM: BK=128B, dbuf 64KiB LDS, 4 waves, 2 blocks/CU =======
// C = A[M][K] * B[N][K]^T via mfma_scale_f32_16x16x128_f8f6f4 (FMT=0 e4m3, unit
// scales 0x7F). R25: OPERAND-SWAPPED (mfma(bv,av)) -> D = C^T fragments: lane holds
// C[row0+p*16+cl][col0+q*16+rg .. +3] (4 consecutive C columns) -> packed stores.
// Fragment k-mapping symmetric => swap exact. LDS swizzle pb = lb ^ (row&7); stage
// pre-swizzles GLOBAL col 16*((l&7)^((l>>3)&7)), linear gload_lds dest.
// Per K-128 tile: 16 b128 reads + 16 MFMA. Counted-vmcnt 2-deep (VMC(8); tail 0).
template <int EPI>
__global__ __launch_bounds__(256, 2) void gemmq_k(
    const u8* __restrict__ Ab, const u8* __restrict__ Bbp, void* __restrict__ Cb,
    const float* __restrict__ bias, const float* __restrict__ resid,
    int K, int lda, int ldb, int ldc, long astr, long bstr, long cstr) {
  extern __shared__ u8 Lq[];  // 2*2*16384 B = 64 KiB
  const int t = threadIdx.x;
  const int lane = t & 63;
  const int w = t >> 6;
  const int wm = w >> 1, wn = w & 1;

  // XCD-chunked band raster (bijective; all grids: nwg%8==0, gx|cpx, H|R)
  const int gx = gridDim.x;
  const int nwg = gx * gridDim.y;
  const int dd = blockIdx.y * gx + blockIdx.x;
  const int cpx = nwg >> 3;
  const int xcd = dd & 7;
  const int idx = dd >> 3;
  const int R = cpx / gx;
  const int H = (R >= 8) ? 8 : R;
  const int bandsz = H * gx;
  const int bnd = idx / bandsz;
  const int rr = idx % bandsz;
  const int m_t = xcd * R + bnd * H + (rr % H);
  const int n_t = rr / H;
  const int m0 = m_t * 128;
  const int n0 = n_t * 128;

  const long z = blockIdx.z;
  const u8* A;
  if constexpr (EPI == EPI_RESID) {
    const long qo[4] = {0, 67108864, 100663296, 134217728};  // h quarter byte offsets
    A = Ab + qo[m0 >> 12] - (long)(m0 & ~4095) * lda;
  } else if constexpr (EPI == EPI_AOS) {
    A = (z < 4) ? Ab + z * astr : (const u8*)bias + (z - 4) * astr;  // probs slabs
  } else if constexpr (EPI == EPI_SWISH || EPI == EPI_QKV) {
    A = Ab;
  } else {  // EPI_SCORE (per-batch)
    A = Ab + z * astr;
  }
  const u8* Bp = Bbp + z * bstr;

  // staging: chunk = 8 rows x 128B = 1KB; 16 chunks/op; wave w stages chunks 4w..4w+3
  const int lrow = lane >> 3;                            // row within chunk (0..7)
  const int sc = 16 * ((lane & 7) ^ ((lane >> 3) & 7));  // pre-swizzled byte col
  const u8* gA[4];
  const u8* gB[4];
#pragma unroll
  for (int j = 0; j < 4; ++j) {
    const int r = (w * 4 + j) * 8 + lrow;
    gA[j] = A + (long)(m0 + r) * lda + sc;
    gB[j] = Bp + (long)(n0 + r) * ldb + sc;
  }

#define QSTAGE(buf, tau)                                                         \
  do {                                                                           \
    _Pragma("unroll") for (int j_ = 0; j_ < 4; ++j_)                             \
        gload16(gA[j_] + (long)(tau) * 128,                                      \
                &Lq[(buf)*32768 + (w * 4 + j_) * 1024]);                         \
    _Pragma("unroll") for (int j_ = 0; j_ < 4; ++j_)                             \
        gload16(gB[j_] + (long)(tau) * 128,                                      \
                &Lq[(buf)*32768 + 16384 + (w * 4 + j_) * 1024]);                 \
  } while (0)

  const int rA = lane & 15;
  const int g2 = (lane >> 4) * 2;  // logical 16B-block pair base (k in [32g,32g+32))

  // loads land directly in the operand halves (no element-wise repack)
#define QREAD_ALL(base)                                                          \
  _Pragma("unroll") for (int q_ = 0; q_ < 4; ++q_) {                             \
    const int ra_ = wm * 64 + q_ * 16 + rA;                                      \
    const int rb_ = wn * 64 + q_ * 16 + rA;                                      \
    i32x4* ah_ = (i32x4*)&av[q_];                                                \
    i32x4* bh_ = (i32x4*)&bv[q_];                                                \
    ah_[0] = *(const i32x4*)&Lq[(base) + ra_ * 128 + ((g2 ^ (ra_ & 7)) << 4)];   \
    ah_[1] = *(const i32x4*)&Lq[(base) + ra_ * 128 +                             \
                                (((g2 + 1) ^ (ra_ & 7)) << 4)];                  \
    bh_[0] = *(const i32x4*)&Lq[(base) + 16384 + rb_ * 128 +                     \
                                ((g2 ^ (rb_ & 7)) << 4)];                        \
    bh_[1] = *(const i32x4*)&Lq[(base) + 16384 + rb_ * 128 +                     \
                                (((g2 + 1) ^ (rb_ & 7)) << 4)];                  \
  }
// operand-swapped: acc[q][p] = B_q x A_p (= C^T fragment)
#define QMFMA_ALL()                                                              \
  do {                                                                           \
    SETP(1);                                                                     \
    _Pragma("unroll") for (int q = 0; q < 4; ++q)                                \
    _Pragma("unroll") for (int p = 0; p < 4; ++p)                                \
        acc[q][p] = __builtin_amdgcn_mfma_scale_f32_16x16x128_f8f6f4(            \
            bv[q], av[p], acc[q][p], 0, 0, 0, 0x7F, 0, 0x7F);                    \
    SETP(0);                                                                     \
  } while (0)

  f32x4 acc[4][4] = {};
  i32x8 av[4], bv[4];

  QSTAGE(0, 0);
  QSTAGE(1, 1);

  const int NT = K >> 7;  // even for all dispatches (8/8/16/8/32)
  for (int tt = 0; tt < NT; tt += 2) {
    VMC(8);      // own stage(tt) landed (8 newer = own stage(tt+1))
    BARRIER();
    QREAD_ALL(0);
    QMFMA_ALL();
    BARRIER();
    if (tt + 2 < NT) QSTAGE(0, tt + 2);
    if (tt + 2 < NT) VMC(8); else VMC(0);  // tail: full drain
    BARRIER();
    QREAD_ALL(32768);
    QMFMA_ALL();
    BARRIER();
    if (tt + 3 < NT) QSTAGE(1, tt + 3);
  }

  // epilogue (C^T fragments): lane holds C[gm][gn..gn+3], gm = row0+p*16+cl,
  // gn = col0+q*16+rg (gn % 4 == 0 -> all packed stores aligned).
  const int row0 = m0 + wm * 64;
  const int col0 = n0 + wn * 64;
  const int cl = lane & 15;
  const int rg = (lane >> 4) * 4;
#pragma unroll
  for (int p = 0; p < 4; p++) {
    const long gm = row0 + p * 16 + cl;
#pragma unroll
    for (int q = 0; q < 4; q++) {
      const int gn = col0 + q * 16 + rg;
      f32x4 v4 = acc[q][p];
      if constexpr (EPI == EPI_QKV) {
        // fused N=3072: segment by column (blocks never straddle segments)
        if (n0 < 1024) {
          *(u32*)&((u8*)Cb)[gm * (long)ldc + gn] =
              pack4fp8(v4[0], v4[1], v4[2], v4[3]);                       // q8
        } else if (n0 < 2048) {
          *(u32*)&((u8*)Cb)[16777216L + gm * (long)ldc + (gn & 1023)] =
              pack4fp8(v4[0], v4[1], v4[2], v4[3]);                       // k8
        } else {
          f16x4 h;
#pragma unroll
          for (int j = 0; j < 4; j++) h[j] = (f16)v4[j];
          *(f16x4*)&((f16*)resid)[gm * (long)ldc + (gn & 1023)] = h;      // vrows
        }
      } else if constexpr (EPI == EPI_SCORE) {
        f16* dst = (z < 4) ? (f16*)Cb : (f16*)bias;              // lo/hi slab
        f16x4 h;
#pragma unroll
        for (int j = 0; j < 4; j++) h[j] = (f16)v4[j];
        *(f16x4*)&dst[(z & 3) * cstr + gm * ldc + gn] = h;
      } else if constexpr (EPI == EPI_AOS) {
        // probs were stored x256; post-softmax scale 1/32 -> val/8192
        *(u32*)&((u8*)Cb)[z * cstr + gm * ldc + gn] =
            pack4fp8(v4[0] * (1.0f / 8192.0f), v4[1] * (1.0f / 8192.0f),
                     v4[2] * (1.0f / 8192.0f), v4[3] * (1.0f / 8192.0f));
      } else if constexpr (EPI == EPI_SWISH) {
        const long qoc[4] = {0, 67108864, 100663296, 134217728};  // byte offs
        u8* hq = (u8*)Cb + qoc[m0 >> 12];
        float sw[4];
#pragma unroll
        for (int j = 0; j < 4; j++) {
          float hv = v4[j] + bias[gn + j];
          sw[j] = hv / (1.0f + __expf(-hv));
        }
        *(u32*)&hq[(long)(gm & 4095) * ldc + gn] =
            pack4fp8(sw[0], sw[1], sw[2], sw[3]);
      } else {  // EPI_RESID
        float4 b4 = *(const float4*)&bias[gn];
        float4 r4 = *(const float4*)&resid[gm * (long)ldc + gn];
        float4 o4;
        o4.x = v4[0] + b4.x + r4.x;
        o4.y = v4[1] + b4.y + r4.y;
        o4.z = v4[2] + b4.z + r4.z;
        o4.w = v4[3] + b4.w + r4.w;
        *(float4*)&((float*)Cb)[gm * (long)ldc + gn] = o4;
      }
    }
  }
#undef QSTAGE
#undef QREAD_ALL
#undef QMFMA_ALL
}

extern "C" void kernel_launch(void* const* d_in, const int* in_sizes, int n_in,
                              void* d_out, int out_size, void* d_ws, size_t ws_size,
                              hipStream_t stream) {
  const float* x  = (const float*)d_in[0];
  const float* g  = (const float*)d_in[1];
  const float* be = (const float*)d_in[2];
  const float* Wq = (const float*)d_in[3];
  const float* Wk = (const float*)d_in[4];
  const float* Wv = (const float*)d_in[5];
  const float* W1 = (const float*)d_in[6];
  const float* b1 = (const float*)d_in[7];
  const float* W2 = (const float*)d_in[8];
  const float* b2 = (const float*)d_in[9];

  hipFuncSetAttribute((const void*)&gemmq_k<EPI_QKV>,
                      hipFuncAttributeMaxDynamicSharedMemorySize, 65536);
  hipFuncSetAttribute((const void*)&gemmq_k<EPI_SCORE>,
                      hipFuncAttributeMaxDynamicSharedMemorySize, 65536);
  hipFuncSetAttribute((const void*)&gemmq_k<EPI_AOS>,
                      hipFuncAttributeMaxDynamicSharedMemorySize, 65536);
  hipFuncSetAttribute((const void*)&gemmq_k<EPI_SWISH>,
                      hipFuncAttributeMaxDynamicSharedMemorySize, 65536);
  hipFuncSetAttribute((const void*)&gemmq_k<EPI_RESID>,
                      hipFuncAttributeMaxDynamicSharedMemorySize, 65536);

  // ---- workspace overlay (bytes); identical to R17/R22/R23 ----
  char* ws = (char*)d_ws;
  u8*   xn8       = (u8*)(ws + 0);
  f16*  scores_lo = (f16*)(ws + 0);            // after xn8 dies (post-QKV)
  u8*   q8        = (u8*)(ws + 33554432);      // k8 contiguous at +16M
  u8*   ao8       = (u8*)(ws + 33554432);      // after q8 dies (post-scores)
  u8*   k8        = (u8*)(ws + 50331648);
  f16*  vrows     = (f16*)(ws + 67108864);     // f16 [16384][1024]
  f16*  scores_hi = (f16*)(ws + 100663296);
  u8*   vT8       = (u8*)(ws + 134217728);     // [8][1024][2048]
  u8*   wq8       = (u8*)(ws + 167772160);     // wq/wk/wv fp8, contiguous [3072][1024]
  u8*   w1T8      = (u8*)(ws + 170917888);     // [4096][1024] fp8
  u8*   w2T8      = (u8*)(ws + 175112192);     // [1024][4096] fp8
  // h quarters (fp8) at {0, 67108864, 100663296, 134217728} (EPI_SWISH/RESID).

  tcast8_k<<<dim3(32, 32), 256, 0, stream>>>(Wq, wq8, 1024, 1024);
  tcast8_k<<<dim3(32, 32), 256, 0, stream>>>(Wk, wq8 + 1048576, 1024, 1024);
  tcast8_k<<<dim3(32, 32), 256, 0, stream>>>(Wv, wq8 + 2097152, 1024, 1024);
  tcast8_k<<<dim3(128, 32), 256, 0, stream>>>(W1, w1T8, 1024, 4096);
  tcast8_k<<<dim3(32, 128), 256, 0, stream>>>(W2, w2T8, 4096, 1024);

  ln8_k<<<16384, 256, 0, stream>>>(x, g, be, xn8);

  // QKV (MX fp8, FUSED N=3072): cols 0..1023 -> q8, 1024..2047 -> k8, 2048.. -> vrows
  gemmq_k<EPI_QKV><<<dim3(24, 128, 1), 256, 65536, stream>>>(
      xn8, wq8, q8, nullptr, (const float*)vrows,
      1024, 1024, 1024, 1024, 0L, 0L, 0L);

  tv8_k<<<dim3(16, 32, 8), 256, 0, stream>>>(vrows, vT8);

  // scores (MX fp8 -> f16), all 8 batches; hi slab via bias ptr
  gemmq_k<EPI_SCORE><<<dim3(16, 16, 8), 256, 65536, stream>>>(
      q8, k8, scores_lo, (const float*)scores_hi, nullptr,
      1024, 1024, 1024, 2048, 2097152L, 2097152L, 4194304L);

  softmax8_k<<<16384, 256, 0, stream>>>(scores_lo, scores_hi);

  // PV (MX fp8 probs x vT -> ao fp8), all 8 batches; probs_hi via bias ptr
  gemmq_k<EPI_AOS><<<dim3(8, 16, 8), 256, 65536, stream>>>(
      (const u8*)scores_lo, vT8, ao8, (const float*)scores_hi, nullptr,
      2048, 4096, 2048, 1024, 8388608L, 2097152L, 2097152L);

  // MLP1 (MX fp8): h (quartered fp8) = swish(ao @ W1 + b1)
  gemmq_k<EPI_SWISH><<<dim3(32, 128, 1), 256, 65536, stream>>>(
      ao8, w1T8, ws, b1, nullptr, 1024, 1024, 1024, 4096, 0L, 0L, 0L);
  // MLP2 (MX fp8): out = h @ W2 + b2 + x
  gemmq_k<EPI_RESID><<<dim3(8, 128, 1), 256, 65536, stream>>>(
      (const u8*)ws, w2T8, d_out, b2, x, 4096, 4096, 4096, 1024, 0L, 0L, 0L);
}

// Round 26
// 393.387 us; speedup vs baseline: 1.0933x; 1.0933x over previous
//
#include <hip/hip_runtime.h>
#include <hip/hip_fp8.h>

// EncoderBlock: B=8, S=2048, D=1024, H=4096, single-head attn (scale AFTER softmax),
// LN -> QKV -> scores -> softmax*(1/32) -> PV -> MLP(Swish) -> +residual.
// Round 26: REVERT to R24 exactly (session best, 393.8us = 4.33x over R1 baseline).
// R25's C^T-epilogue traded instruction count for store coalescing and lost; the
// R24 orientation (16 consecutive bytes per 16-lane group per store) is optimal for
// row-major outputs. Final configuration: full MX-scaled fp8 e4m3 compute path
// (mfma_scale 16x16x128, unit scales), BK=128 dbuf 64KiB, counted-vmcnt 2-deep,
// 2 blocks/CU, XCD band raster, fused QKV (N=3072), fp8 probs x256, fused epilogues.
// WS = 190,840,832 B.

#define Bb_ 8
#define Ss_ 2048
#define Dd_ 1024
#define Hh_ 4096

typedef __bf16 bf16;
typedef _Float16 f16;
typedef unsigned char u8;
typedef unsigned int u32;
typedef unsigned long long u64;
typedef __attribute__((ext_vector_type(8))) _Float16 f16x8;
typedef __attribute__((ext_vector_type(4))) float f32x4;
typedef __attribute__((ext_vector_type(4))) int i32x4;
typedef __attribute__((ext_vector_type(8))) int i32x8;

enum { EPI_QKV = 0, EPI_SCORE = 1, EPI_AOS = 2, EPI_SWISH = 3, EPI_RESID = 4 };

__device__ __forceinline__ void gload16(const void* g, void* l) {
  __builtin_amdgcn_global_load_lds(
      (const __attribute__((address_space(1))) void*)g,
      (__attribute__((address_space(3))) void*)l, 16, 0, 0);
}

__device__ __forceinline__ u8 to_fp8(float f) {
  __hip_fp8_e4m3 v(f);  // OCP e4m3fn (gfx950 native)
  return (u8)v.__x;
}

#define SETP(x) __builtin_amdgcn_s_setprio(x)
#define BARRIER()                          \
  do {                                     \
    asm volatile("" ::: "memory");         \
    __builtin_amdgcn_s_barrier();          \
    asm volatile("" ::: "memory");         \
  } while (0)
#define VMC(n) asm volatile("s_waitcnt vmcnt(" #n ")" ::: "memory")

// ---------- transpose-cast: W[K][N] f32 -> WT[N][K] fp8 e4m3 ----------
__global__ __launch_bounds__(256) void tcast8_k(const float* __restrict__ W,
                                                u8* __restrict__ WT, int K, int N) {
  __shared__ float tile[32][33];
  const int tn0 = blockIdx.x * 32;
  const int tk0 = blockIdx.y * 32;
  const int t = threadIdx.x;
  const int c = t & 31;
  const int r4 = t >> 5;
#pragma unroll
  for (int i = 0; i < 4; i++) {
    int r = r4 + i * 8;
    tile[r][c] = W[(long)(tk0 + r) * N + (tn0 + c)];
  }
  __syncthreads();
#pragma unroll
  for (int i = 0; i < 4; i++) {
    int r = r4 + i * 8;
    WT[(long)(tn0 + r) * K + (tk0 + c)] = to_fp8(tile[c][r]);
  }
}

// ---------- v transpose+cast: vrows f16 [z][2048][1024] -> vT8 u8 [z][1024][2048] ----
__global__ __launch_bounds__(256) void tv8_k(const f16* __restrict__ V,
                                             u8* __restrict__ VT) {
  __shared__ f16 tile[64][72];
  const long z = blockIdx.z;
  const int n0 = blockIdx.x * 64;
  const int k0 = blockIdx.y * 64;
  const int t = threadIdx.x;
  const int r = t >> 3;
  const int c = (t & 7) * 8;
  const f16* Vb = V + z * (long)(Ss_ * Dd_);
  u8* VTb = VT + z * (long)(Dd_ * Ss_);
#pragma unroll
  for (int i = 0; i < 2; i++)
    *(f16x8*)&tile[r + i * 32][c] =
        *(const f16x8*)(Vb + (long)(k0 + r + i * 32) * Dd_ + n0 + c);
  __syncthreads();
#pragma unroll
  for (int i = 0; i < 2; i++) {
    const int n = r + i * 32;
    union { u8 b[8]; u64 w; } ov;
#pragma unroll
    for (int j = 0; j < 8; j++) ov.b[j] = to_fp8((float)tile[c + j][n]);
    *(u64*)(VTb + (long)(n0 + n) * Ss_ + k0 + c) = ov.w;
  }
}

// ---------- LayerNorm: x[row][1024] f32 -> xn fp8 ----------
__global__ __launch_bounds__(256) void ln8_k(const float* __restrict__ x,
                                             const float* __restrict__ gamma,
                                             const float* __restrict__ beta,
                                             u8* __restrict__ xn) {
  const long row = blockIdx.x;
  const float* xr = x + row * Dd_;
  const int t = threadIdx.x;
  float4 v = *(const float4*)(xr + t * 4);
  float s = v.x + v.y + v.z + v.w;
  float sq = v.x * v.x + v.y * v.y + v.z * v.z + v.w * v.w;
#pragma unroll
  for (int o = 32; o > 0; o >>= 1) {
    s += __shfl_down(s, o);
    sq += __shfl_down(sq, o);
  }
  __shared__ float ls[4], lq[4];
  const int wid = t >> 6;
  if ((t & 63) == 0) { ls[wid] = s; lq[wid] = sq; }
  __syncthreads();
  if (t == 0) {
    float S = ls[0] + ls[1] + ls[2] + ls[3];
    float Q = lq[0] + lq[1] + lq[2] + lq[3];
    float mu = S * (1.0f / Dd_);
    float var = Q * (1.0f / Dd_) - mu * mu;
    ls[0] = mu;
    lq[0] = rsqrtf(var + 1e-5f);
  }
  __syncthreads();
  const float mu = ls[0], rstd = lq[0];
  float4 g = *(const float4*)(gamma + t * 4);
  float4 be = *(const float4*)(beta + t * 4);
  u32 pk = (u32)to_fp8((v.x - mu) * rstd * g.x + be.x) |
           ((u32)to_fp8((v.y - mu) * rstd * g.y + be.y) << 8) |
           ((u32)to_fp8((v.z - mu) * rstd * g.z + be.z) << 16) |
           ((u32)to_fp8((v.w - mu) * rstd * g.w + be.w) << 24);
  *(u32*)(xn + row * (long)Dd_ + t * 4) = pk;
}

// ---------- softmax: f16 scores (two slabs) -> fp8 probs x256, in place ----------
__global__ __launch_bounds__(256) void softmax8_k(f16* __restrict__ lo,
                                                  f16* __restrict__ hi) {
  const long row = blockIdx.x;
  const long z = row >> 11;
  f16* sr = (z < 4 ? lo + z * 4194304L : hi + (z - 4) * 4194304L) +
            (row & 2047) * (long)Ss_;
  const int t = threadIdx.x;
  f16x8 v = *(const f16x8*)(sr + t * 8);
  float f[8];
#pragma unroll
  for (int j = 0; j < 8; j++) f[j] = (float)v[j];
  float vm = f[0];
#pragma unroll
  for (int j = 1; j < 8; j++) vm = fmaxf(vm, f[j]);
  __shared__ float red[4];
#pragma unroll
  for (int o = 32; o > 0; o >>= 1) vm = fmaxf(vm, __shfl_xor(vm, o));
  const int wid = t >> 6;
  if ((t & 63) == 0) red[wid] = vm;
  __syncthreads();
  vm = fmaxf(fmaxf(red[0], red[1]), fmaxf(red[2], red[3]));
  float e[8], s = 0.f;
#pragma unroll
  for (int j = 0; j < 8; j++) { e[j] = __expf(f[j] - vm); s += e[j]; }
#pragma unroll
  for (int o = 32; o > 0; o >>= 1) s += __shfl_xor(s, o);
  __syncthreads();
  if ((t & 63) == 0) red[wid] = s;
  __syncthreads();
  s = red[0] + red[1] + red[2] + red[3];
  const float rs = 256.0f / s;  // x256: avoids e4m3 subnormals; /8192 in PV epilogue
  union { u8 b[8]; u64 w; } ov;
#pragma unroll
  for (int j = 0; j < 8; j++) ov.b[j] = to_fp8(e[j] * rs);
  *(u64*)((u8*)sr + t * 8) = ov.w;
}

// ====== MX fp8 128x128xK GEMM: BK=128B, dbuf 64KiB LDS, 4 waves, 2 blocks/CU =======
// C = A[M][K] * B[N][K]^T via mfma_scale_f32_16x16x128_f8f6f4 (FMT=0 e4m3, unit
// scales 0x7F). Fragment: row/col = lane&15; lane-group g holds k in [32g,32g+32)
// (A/B symmetric => consistent k-permutation exact). LDS swizzle pb = lb ^ (row&7);
// stage pre-swizzles GLOBAL col 16*((l&7)^((l>>3)&7)), linear gload_lds dest.
// QREAD loads land directly in i32x8 halves (no element repack).
// Per K-128 tile: 16 b128 reads + 16 MFMA. Counted-vmcnt 2-deep (VMC(8); tail 0).
template <int EPI>
__global__ __launch_bounds__(256, 2) void gemmq_k(
    const u8* __restrict__ Ab, const u8* __restrict__ Bbp, void* __restrict__ Cb,
    const float* __restrict__ bias, const float* __restrict__ resid,
    int K, int lda, int ldb, int ldc, long astr, long bstr, long cstr) {
  extern __shared__ u8 Lq[];  // 2*2*16384 B = 64 KiB
  const int t = threadIdx.x;
  const int lane = t & 63;
  const int w = t >> 6;
  const int wm = w >> 1, wn = w & 1;

  // XCD-chunked band raster (bijective; all grids: nwg%8==0, gx|cpx, H|R)
  const int gx = gridDim.x;
  const int nwg = gx * gridDim.y;
  const int dd = blockIdx.y * gx + blockIdx.x;
  const int cpx = nwg >> 3;
  const int xcd = dd & 7;
  const int idx = dd >> 3;
  const int R = cpx / gx;
  const int H = (R >= 8) ? 8 : R;
  const int bandsz = H * gx;
  const int bnd = idx / bandsz;
  const int rr = idx % bandsz;
  const int m_t = xcd * R + bnd * H + (rr % H);
  const int n_t = rr / H;
  const int m0 = m_t * 128;
  const int n0 = n_t * 128;

  const long z = blockIdx.z;
  const u8* A;
  if constexpr (EPI == EPI_RESID) {
    const long qo[4] = {0, 67108864, 100663296, 134217728};  // h quarter byte offsets
    A = Ab + qo[m0 >> 12] - (long)(m0 & ~4095) * lda;
  } else if constexpr (EPI == EPI_AOS) {
    A = (z < 4) ? Ab + z * astr : (const u8*)bias + (z - 4) * astr;  // probs slabs
  } else if constexpr (EPI == EPI_SWISH || EPI == EPI_QKV) {
    A = Ab;
  } else {  // EPI_SCORE (per-batch)
    A = Ab + z * astr;
  }
  const u8* Bp = Bbp + z * bstr;

  // staging: chunk = 8 rows x 128B = 1KB; 16 chunks/op; wave w stages chunks 4w..4w+3
  const int lrow = lane >> 3;                            // row within chunk (0..7)
  const int sc = 16 * ((lane & 7) ^ ((lane >> 3) & 7));  // pre-swizzled byte col
  const u8* gA[4];
  const u8* gB[4];
#pragma unroll
  for (int j = 0; j < 4; ++j) {
    const int r = (w * 4 + j) * 8 + lrow;
    gA[j] = A + (long)(m0 + r) * lda + sc;
    gB[j] = Bp + (long)(n0 + r) * ldb + sc;
  }

#define QSTAGE(buf, tau)                                                         \
  do {                                                                           \
    _Pragma("unroll") for (int j_ = 0; j_ < 4; ++j_)                             \
        gload16(gA[j_] + (long)(tau) * 128,                                      \
                &Lq[(buf)*32768 + (w * 4 + j_) * 1024]);                         \
    _Pragma("unroll") for (int j_ = 0; j_ < 4; ++j_)                             \
        gload16(gB[j_] + (long)(tau) * 128,                                      \
                &Lq[(buf)*32768 + 16384 + (w * 4 + j_) * 1024]);                 \
  } while (0)

  const int rA = lane & 15;
  const int g2 = (lane >> 4) * 2;  // logical 16B-block pair base (k in [32g,32g+32))

  // loads land directly in the operand halves (no element-wise repack)
#define QREAD_ALL(base)                                                          \
  _Pragma("unroll") for (int q_ = 0; q_ < 4; ++q_) {                             \
    const int ra_ = wm * 64 + q_ * 16 + rA;                                      \
    const int rb_ = wn * 64 + q_ * 16 + rA;                                      \
    i32x4* ah_ = (i32x4*)&av[q_];                                                \
    i32x4* bh_ = (i32x4*)&bv[q_];                                                \
    ah_[0] = *(const i32x4*)&Lq[(base) + ra_ * 128 + ((g2 ^ (ra_ & 7)) << 4)];   \
    ah_[1] = *(const i32x4*)&Lq[(base) + ra_ * 128 +                             \
                                (((g2 + 1) ^ (ra_ & 7)) << 4)];                  \
    bh_[0] = *(const i32x4*)&Lq[(base) + 16384 + rb_ * 128 +                     \
                                ((g2 ^ (rb_ & 7)) << 4)];                        \
    bh_[1] = *(const i32x4*)&Lq[(base) + 16384 + rb_ * 128 +                     \
                                (((g2 + 1) ^ (rb_ & 7)) << 4)];                  \
  }
#define QMFMA_ALL()                                                              \
  do {                                                                           \
    SETP(1);                                                                     \
    _Pragma("unroll") for (int q = 0; q < 4; ++q)                                \
    _Pragma("unroll") for (int p = 0; p < 4; ++p)                                \
        acc[q][p] = __builtin_amdgcn_mfma_scale_f32_16x16x128_f8f6f4(            \
            av[q], bv[p], acc[q][p], 0, 0, 0, 0x7F, 0, 0x7F);                    \
    SETP(0);                                                                     \
  } while (0)

  f32x4 acc[4][4] = {};
  i32x8 av[4], bv[4];

  QSTAGE(0, 0);
  QSTAGE(1, 1);

  const int NT = K >> 7;  // even for all dispatches (8/8/16/8/32)
  for (int tt = 0; tt < NT; tt += 2) {
    VMC(8);      // own stage(tt) landed (8 newer = own stage(tt+1))
    BARRIER();
    QREAD_ALL(0);
    QMFMA_ALL();
    BARRIER();
    if (tt + 2 < NT) QSTAGE(0, tt + 2);
    if (tt + 2 < NT) VMC(8); else VMC(0);  // tail: full drain
    BARRIER();
    QREAD_ALL(32768);
    QMFMA_ALL();
    BARRIER();
    if (tt + 3 < NT) QSTAGE(1, tt + 3);
  }

  // epilogue: C/D layout col=lane&15, row=(lane>>4)*4+j (shape-determined)
  const int row0 = m0 + wm * 64;
  const int col0 = n0 + wn * 64;
  const int cl = lane & 15;
  const int rg = (lane >> 4) * 4;
#pragma unroll
  for (int mi = 0; mi < 4; mi++) {
#pragma unroll
    for (int ni = 0; ni < 4; ni++) {
#pragma unroll
      for (int j = 0; j < 4; j++) {
        const long gm = row0 + mi * 16 + rg + j;
        const int gn = col0 + ni * 16 + cl;
        float val = acc[mi][ni][j];
        if constexpr (EPI == EPI_QKV) {
          // fused N=3072: segment by column (blocks never straddle segments)
          if (n0 < 1024) {
            ((u8*)Cb)[gm * (long)ldc + gn] = to_fp8(val);                       // q8
          } else if (n0 < 2048) {
            ((u8*)Cb)[16777216L + gm * (long)ldc + (gn & 1023)] = to_fp8(val);  // k8
          } else {
            ((f16*)resid)[gm * (long)ldc + (gn & 1023)] = (f16)val;             // vrows
          }
        } else if constexpr (EPI == EPI_SCORE) {
          f16* dst = (z < 4) ? (f16*)Cb : (f16*)bias;              // lo/hi slab
          dst[(z & 3) * cstr + gm * ldc + gn] = (f16)val;
        } else if constexpr (EPI == EPI_AOS) {
          // probs were stored x256; post-softmax scale 1/32 -> val/8192
          ((u8*)Cb)[z * cstr + gm * ldc + gn] = to_fp8(val * (1.0f / 8192.0f));
        } else if constexpr (EPI == EPI_SWISH) {
          const long qoc[4] = {0, 67108864, 100663296, 134217728};  // byte offs
          u8* hq = (u8*)Cb + qoc[m0 >> 12];
          float hv = val + bias[gn];
          hq[(long)(gm & 4095) * ldc + gn] = to_fp8(hv / (1.0f + __expf(-hv)));
        } else {  // EPI_RESID
          ((float*)Cb)[gm * (long)ldc + gn] = val + bias[gn] + resid[gm * (long)ldc + gn];
        }
      }
    }
  }
#undef QSTAGE
#undef QREAD_ALL
#undef QMFMA_ALL
}

extern "C" void kernel_launch(void* const* d_in, const int* in_sizes, int n_in,
                              void* d_out, int out_size, void* d_ws, size_t ws_size,
                              hipStream_t stream) {
  const float* x  = (const float*)d_in[0];
  const float* g  = (const float*)d_in[1];
  const float* be = (const float*)d_in[2];
  const float* Wq = (const float*)d_in[3];
  const float* Wk = (const float*)d_in[4];
  const float* Wv = (const float*)d_in[5];
  const float* W1 = (const float*)d_in[6];
  const float* b1 = (const float*)d_in[7];
  const float* W2 = (const float*)d_in[8];
  const float* b2 = (const float*)d_in[9];

  hipFuncSetAttribute((const void*)&gemmq_k<EPI_QKV>,
                      hipFuncAttributeMaxDynamicSharedMemorySize, 65536);
  hipFuncSetAttribute((const void*)&gemmq_k<EPI_SCORE>,
                      hipFuncAttributeMaxDynamicSharedMemorySize, 65536);
  hipFuncSetAttribute((const void*)&gemmq_k<EPI_AOS>,
                      hipFuncAttributeMaxDynamicSharedMemorySize, 65536);
  hipFuncSetAttribute((const void*)&gemmq_k<EPI_SWISH>,
                      hipFuncAttributeMaxDynamicSharedMemorySize, 65536);
  hipFuncSetAttribute((const void*)&gemmq_k<EPI_RESID>,
                      hipFuncAttributeMaxDynamicSharedMemorySize, 65536);

  // ---- workspace overlay (bytes); identical to R17/R22/R23 ----
  char* ws = (char*)d_ws;
  u8*   xn8       = (u8*)(ws + 0);
  f16*  scores_lo = (f16*)(ws + 0);            // after xn8 dies (post-QKV)
  u8*   q8        = (u8*)(ws + 33554432);      // k8 contiguous at +16M
  u8*   ao8       = (u8*)(ws + 33554432);      // after q8 dies (post-scores)
  u8*   k8        = (u8*)(ws + 50331648);
  f16*  vrows     = (f16*)(ws + 67108864);     // f16 [16384][1024]
  f16*  scores_hi = (f16*)(ws + 100663296);
  u8*   vT8       = (u8*)(ws + 134217728);     // [8][1024][2048]
  u8*   wq8       = (u8*)(ws + 167772160);     // wq/wk/wv fp8, contiguous [3072][1024]
  u8*   w1T8      = (u8*)(ws + 170917888);     // [4096][1024] fp8
  u8*   w2T8      = (u8*)(ws + 175112192);     // [1024][4096] fp8
  // h quarters (fp8) at {0, 67108864, 100663296, 134217728} (EPI_SWISH/RESID).

  tcast8_k<<<dim3(32, 32), 256, 0, stream>>>(Wq, wq8, 1024, 1024);
  tcast8_k<<<dim3(32, 32), 256, 0, stream>>>(Wk, wq8 + 1048576, 1024, 1024);
  tcast8_k<<<dim3(32, 32), 256, 0, stream>>>(Wv, wq8 + 2097152, 1024, 1024);
  tcast8_k<<<dim3(128, 32), 256, 0, stream>>>(W1, w1T8, 1024, 4096);
  tcast8_k<<<dim3(32, 128), 256, 0, stream>>>(W2, w2T8, 4096, 1024);

  ln8_k<<<16384, 256, 0, stream>>>(x, g, be, xn8);

  // QKV (MX fp8, FUSED N=3072): cols 0..1023 -> q8, 1024..2047 -> k8, 2048.. -> vrows
  gemmq_k<EPI_QKV><<<dim3(24, 128, 1), 256, 65536, stream>>>(
      xn8, wq8, q8, nullptr, (const float*)vrows,
      1024, 1024, 1024, 1024, 0L, 0L, 0L);

  tv8_k<<<dim3(16, 32, 8), 256, 0, stream>>>(vrows, vT8);

  // scores (MX fp8 -> f16), all 8 batches; hi slab via bias ptr
  gemmq_k<EPI_SCORE><<<dim3(16, 16, 8), 256, 65536, stream>>>(
      q8, k8, scores_lo, (const float*)scores_hi, nullptr,
      1024, 1024, 1024, 2048, 2097152L, 2097152L, 4194304L);

  softmax8_k<<<16384, 256, 0, stream>>>(scores_lo, scores_hi);

  // PV (MX fp8 probs x vT -> ao fp8), all 8 batches; probs_hi via bias ptr
  gemmq_k<EPI_AOS><<<dim3(8, 16, 8), 256, 65536, stream>>>(
      (const u8*)scores_lo, vT8, ao8, (const float*)scores_hi, nullptr,
      2048, 4096, 2048, 1024, 8388608L, 2097152L, 2097152L);

  // MLP1 (MX fp8): h (quartered fp8) = swish(ao @ W1 + b1)
  gemmq_k<EPI_SWISH><<<dim3(32, 128, 1), 256, 65536, stream>>>(
      ao8, w1T8, ws, b1, nullptr, 1024, 1024, 1024, 4096, 0L, 0L, 0L);
  // MLP2 (MX fp8): out = h @ W2 + b2 + x
  gemmq_k<EPI_RESID><<<dim3(8, 128, 1), 256, 65536, stream>>>(
      (const u8*)ws, w2T8, d_out, b2, x, 4096, 4096, 4096, 1024, 0L, 0L, 0L);
}